// Round 6
// baseline (1446.418 us; speedup 1.0000x reference)
//
#include <hip/hip_runtime.h>
#include <cstdint>
#include <cstddef>

// GGNN on MI355X. Round 6: numerics identical to rounds 3-5 (3-limb bf16,
// 6 limb-products ascending {11,02,20,01,10,00}, fp32-equivalent).
// adj8 K-loop restructured to the faithful 2-barrier-per-phase schedule:
//   per K-tile (BK=64): 2 phases, each {ds_read issue -> barrier -> lgkmcnt(0)
//   -> sched_barrier -> setprio(1) -> 16 MFMA -> setprio(0) -> barrier};
//   then STAGE(kt+2) + vmcnt(6) (vmcnt(0) on tail) + barrier. 5 barriers/kt.
// Reads issued before the entry barrier let waves slip: LDS pipe and MFMA pipe
// stay concurrently busy (m201 mechanism). Accumulation order per element is
// unchanged -> bit-identical result to round 5.
// Layouts:
//   A2  [2048: Ain|Aout][ l0|l1|l2 (1024 each) ]
//   hN2 [b*128+d][ l0|l1|l2 ]  (adjacency B^T operand; rh3 overlay)
//   X2  [n*32+b][ per-limb 384: m_in(128) m_out(128) h(128) ] x3  (LDX 1152)

typedef __bf16 bf16;
typedef __attribute__((ext_vector_type(8))) __bf16 bf16x8;
typedef __attribute__((ext_vector_type(4))) __bf16 bf16x4;
typedef __attribute__((ext_vector_type(4))) float f32x4;

#define LDX 1152
#define LDH 3072
#define NT 96  // 6 products x (K=1024)/(BK=64)

// ascending limb-product schedule: 11,02,20,01,10,00
static constexpr int SA6[6] = {1, 0, 2, 0, 1, 0};
static constexpr int SB6[6] = {1, 2, 0, 1, 0, 0};

static __device__ __forceinline__ void gload16(const void* g, void* l) {
  __builtin_amdgcn_global_load_lds(
      (const __attribute__((address_space(1))) void*)g,
      (__attribute__((address_space(3))) void*)l, 16, 0, 0);
}

static __device__ __forceinline__ float sigmoidf_(float x) {
  return 1.f / (1.f + expf(-x));
}

static __device__ __forceinline__ unsigned short bc16(bf16 x) {
  return __builtin_bit_cast(unsigned short, x);
}
static __device__ __forceinline__ bf16 bcbf(unsigned short x) {
  return __builtin_bit_cast(bf16, x);
}

// ================= adjacency: 256x128 tile, 8 waves, counted-vmcnt schedule
__global__ __launch_bounds__(512) void adj8(const bf16* __restrict__ A2,
                                            const bf16* __restrict__ hN2,
                                            bf16* __restrict__ X2) {
  __shared__ bf16 sA[2][256 * 64];
  __shared__ bf16 sB[2][128 * 64];
  const int t = threadIdx.x;
  const int wave = t >> 6, lane = t & 63;
  const int wr = wave >> 2;  // 0..1  (M half: 128 rows)
  const int wn = wave & 3;   // 0..3  (N quarter: 32 cols)
  const int m0 = blockIdx.y * 256;
  const int n0 = blockIdx.x * 128;

  f32x4 acc[8][2];
#pragma unroll
  for (int i = 0; i < 8; ++i)
#pragma unroll
    for (int j = 0; j < 2; ++j) acc[i][j] = {0.f, 0.f, 0.f, 0.f};

  // ---- staging: per K-tile = 4 A-gloads + 2 B-gloads per wave (6 vmcnt units)
  // LDS dest linear (wave-uniform base + lane*16B); the DATA for physical slot
  // (t&7) comes from inverse-swizzled global slot (t&7)^(row&7).
  const int srow = t >> 3;                 // 0..63 within a 64-row chunk
  const int sslot = (t & 7) ^ (srow & 7);  // pre-swizzled global 16B slot
  const int wbase = wave * 512;            // elems; wave-uniform LDS base

#define STAGE(buf, kt)                                                              \
  {                                                                                 \
    const int p_ = (kt) >> 4;                                                       \
    const int k0_ = ((kt) & 15) << 6;                                               \
    const int aoff_ = SA6[p_] * 1024 + k0_ + sslot * 8;                             \
    const int boff_ = SB6[p_] * 1024 + k0_ + sslot * 8;                             \
    _Pragma("unroll") for (int g = 0; g < 4; ++g)                                   \
        gload16(A2 + (size_t)(m0 + g * 64 + srow) * LDH + aoff_,                    \
                &sA[buf][g * 4096 + wbase]);                                        \
    _Pragma("unroll") for (int g = 0; g < 2; ++g)                                   \
        gload16(hN2 + (size_t)(n0 + g * 64 + srow) * LDH + boff_,                   \
                &sB[buf][g * 4096 + wbase]);                                        \
  }

  const int frow = lane & 15;
  const int fk = lane >> 4;  // 0..3 (16B slot within K=64 row before swizzle)

  STAGE(0, 0);
  STAGE(1, 1);
  asm volatile("s_waitcnt vmcnt(6)" ::: "memory");  // buf0 landed
  __builtin_amdgcn_s_barrier();

  for (int kt = 0; kt < NT; ++kt) {
    const int cur = kt & 1;

    // ---- phase A: B-frags + A quadrants 0,1 (12 ds_read_b128), then 16 MFMA
    bf16x8 bF[2][2], a0[2][2], a1[2][2];
#pragma unroll
    for (int nf = 0; nf < 2; ++nf)
#pragma unroll
      for (int ks = 0; ks < 2; ++ks) {
        const int row = wn * 32 + nf * 16 + frow;
        const int slot = ((ks << 2) + fk) ^ (row & 7);
        bF[nf][ks] = *(const bf16x8*)&sB[cur][row * 64 + slot * 8];
      }
#pragma unroll
    for (int mi = 0; mi < 2; ++mi)
#pragma unroll
      for (int ks = 0; ks < 2; ++ks) {
        const int row0 = wr * 128 + mi * 16 + frow;
        const int s0 = ((ks << 2) + fk) ^ (row0 & 7);
        a0[mi][ks] = *(const bf16x8*)&sA[cur][row0 * 64 + s0 * 8];
        const int row1 = wr * 128 + (2 + mi) * 16 + frow;
        const int s1 = ((ks << 2) + fk) ^ (row1 & 7);
        a1[mi][ks] = *(const bf16x8*)&sA[cur][row1 * 64 + s1 * 8];
      }
    __builtin_amdgcn_s_barrier();
    asm volatile("s_waitcnt lgkmcnt(0)" ::: "memory");
    __builtin_amdgcn_sched_barrier(0);
    __builtin_amdgcn_s_setprio(1);
#pragma unroll
    for (int mi = 0; mi < 2; ++mi)
#pragma unroll
      for (int nf = 0; nf < 2; ++nf)
#pragma unroll
        for (int ks = 0; ks < 2; ++ks)
          acc[mi][nf] = __builtin_amdgcn_mfma_f32_16x16x32_bf16(
              a0[mi][ks], bF[nf][ks], acc[mi][nf], 0, 0, 0);
#pragma unroll
    for (int mi = 0; mi < 2; ++mi)
#pragma unroll
      for (int nf = 0; nf < 2; ++nf)
#pragma unroll
        for (int ks = 0; ks < 2; ++ks)
          acc[2 + mi][nf] = __builtin_amdgcn_mfma_f32_16x16x32_bf16(
              a1[mi][ks], bF[nf][ks], acc[2 + mi][nf], 0, 0, 0);
    __builtin_amdgcn_s_setprio(0);
    __builtin_amdgcn_s_barrier();

    // ---- phase B: A quadrants 2,3 (8 ds_read_b128), then 16 MFMA
    bf16x8 a2[2][2], a3[2][2];
#pragma unroll
    for (int mi = 0; mi < 2; ++mi)
#pragma unroll
      for (int ks = 0; ks < 2; ++ks) {
        const int row2 = wr * 128 + (4 + mi) * 16 + frow;
        const int s2 = ((ks << 2) + fk) ^ (row2 & 7);
        a2[mi][ks] = *(const bf16x8*)&sA[cur][row2 * 64 + s2 * 8];
        const int row3 = wr * 128 + (6 + mi) * 16 + frow;
        const int s3 = ((ks << 2) + fk) ^ (row3 & 7);
        a3[mi][ks] = *(const bf16x8*)&sA[cur][row3 * 64 + s3 * 8];
      }
    __builtin_amdgcn_s_barrier();
    asm volatile("s_waitcnt lgkmcnt(0)" ::: "memory");
    __builtin_amdgcn_sched_barrier(0);
    __builtin_amdgcn_s_setprio(1);
#pragma unroll
    for (int mi = 0; mi < 2; ++mi)
#pragma unroll
      for (int nf = 0; nf < 2; ++nf)
#pragma unroll
        for (int ks = 0; ks < 2; ++ks)
          acc[4 + mi][nf] = __builtin_amdgcn_mfma_f32_16x16x32_bf16(
              a2[mi][ks], bF[nf][ks], acc[4 + mi][nf], 0, 0, 0);
#pragma unroll
    for (int mi = 0; mi < 2; ++mi)
#pragma unroll
      for (int nf = 0; nf < 2; ++nf)
#pragma unroll
        for (int ks = 0; ks < 2; ++ks)
          acc[6 + mi][nf] = __builtin_amdgcn_mfma_f32_16x16x32_bf16(
              a3[mi][ks], bF[nf][ks], acc[6 + mi][nf], 0, 0, 0);
    __builtin_amdgcn_s_setprio(0);
    __builtin_amdgcn_s_barrier();

    // ---- stage next-next tile into buf[cur] (all reads of it are done)
    if (kt + 2 < NT) {
      STAGE(cur, kt + 2);
      asm volatile("s_waitcnt vmcnt(6)" ::: "memory");  // kt+1's loads landed
    } else {
      asm volatile("s_waitcnt vmcnt(0)" ::: "memory");
    }
    __builtin_amdgcn_s_barrier();
  }
#undef STAGE

  // epilogue: C/D layout col=lane&15, row=(lane>>4)*4+j; 3-limb X2 split
  const int rb = m0 + wr * 128 + (lane >> 4) * 4;
  const int cb = n0 + wn * 32 + (lane & 15);
#pragma unroll
  for (int mf = 0; mf < 8; ++mf)
#pragma unroll
    for (int nf = 0; nf < 2; ++nf)
#pragma unroll
      for (int j = 0; j < 4; ++j) {
        const int gr = rb + mf * 16 + j;
        const int gc = cb + nf * 16;
        const float v = acc[mf][nf][j];
        const int node = gr & 1023;
        const int coff = (gr >> 10) * 128;  // 0: m_in, 128: m_out
        const int bb = gc >> 7, d = gc & 127;
        bf16* px = X2 + ((size_t)node * 32 + bb) * LDX + coff + d;
        const bf16 l0 = (bf16)v;
        float r = v - (float)l0;
        const bf16 l1 = (bf16)r;
        r -= (float)l1;
        px[0] = l0;
        px[384] = l1;
        px[768] = (bf16)r;
      }
}

// ================= (unchanged below: dense/u5/pack/ew/init)
static __device__ __forceinline__ void gemm_seg(const bf16* __restrict__ Ao, int lda,
                                                const bf16* __restrict__ Wo, int ldw,
                                                int Kseg, bf16* lA, bf16* lW,
                                                f32x4 (&acc)[4][4]) {
  const int t = threadIdx.x;
  const int wave = t >> 6, lane = t & 63;
  const int wr = wave >> 1, wc = wave & 1;
  const int srow = t >> 2, scol = (t & 3) * 8;
  const int frow = lane & 15, kfr = (lane >> 4) * 8;
  for (int kk = 0; kk < Kseg; kk += 32) {
    const bf16* ga = Ao + (size_t)srow * lda + kk + scol;
    bf16* la = lA + wave * 512;
    gload16(ga, la);
    gload16(ga + (size_t)64 * lda, la + 2048);
    const bf16* gw = Wo + (size_t)srow * ldw + kk + scol;
    bf16* lw = lW + wave * 512;
    gload16(gw, lw);
    gload16(gw + (size_t)64 * ldw, lw + 2048);
    __syncthreads();
    bf16x8 af[4], wf[4];
#pragma unroll
    for (int m = 0; m < 4; ++m)
      af[m] = *(const bf16x8*)(lA + (wr * 64 + m * 16 + frow) * 32 + kfr);
#pragma unroll
    for (int n = 0; n < 4; ++n)
      wf[n] = *(const bf16x8*)(lW + (wc * 64 + n * 16 + frow) * 32 + kfr);
#pragma unroll
    for (int m = 0; m < 4; ++m)
#pragma unroll
      for (int n = 0; n < 4; ++n)
        acc[m][n] = __builtin_amdgcn_mfma_f32_16x16x32_bf16(af[m], wf[n], acc[m][n], 0, 0, 0);
    __syncthreads();
  }
}

#define ACC_ZERO(acc)                          \
  _Pragma("unroll") for (int i = 0; i < 4; ++i) \
  _Pragma("unroll") for (int j = 0; j < 4; ++j) acc[i][j] = {0.f, 0.f, 0.f, 0.f};

#define EPILOG_IDX                                          \
  const int t = threadIdx.x;                                \
  const int wave = t >> 6, lane = t & 63;                   \
  const int rb = (wave >> 1) * 64 + (lane >> 4) * 4;        \
  const int cb = (wave & 1) * 64 + (lane & 15);

__global__ __launch_bounds__(256) void dense_gemm(const bf16* __restrict__ X2,
                                                  const bf16* __restrict__ Wsm,
                                                  const bf16* __restrict__ u3wb,
                                                  const float* __restrict__ u3b,
                                                  float* __restrict__ pre,
                                                  float* __restrict__ u3f) {
  __shared__ bf16 lA[4096];
  __shared__ bf16 lW[4096];
  const int m0 = blockIdx.y * 128;
  const int bx = blockIdx.x;
  f32x4 acc[4][4];
  ACC_ZERO(acc);
  if (bx < 3) {
    const bf16* Ab = X2 + (size_t)m0 * LDX;
    const bf16* Wb = Wsm + (size_t)(bx * 128) * 768;
#pragma unroll
    for (int p = 0; p < 6; ++p)
      gemm_seg(Ab + SA6[p] * 384, LDX, Wb + SB6[p] * 256, 768, 256, lA, lW, acc);
    EPILOG_IDX;
#pragma unroll
    for (int m = 0; m < 4; ++m)
#pragma unroll
      for (int n = 0; n < 4; ++n)
#pragma unroll
        for (int j = 0; j < 4; ++j)
          pre[(size_t)(m0 + rb + m * 16 + j) * 384 + bx * 128 + cb + n * 16] = acc[m][n][j];
  } else {
    const bf16* Ab = X2 + (size_t)m0 * LDX + 256;
#pragma unroll
    for (int p = 0; p < 6; ++p)
      gemm_seg(Ab + SA6[p] * 384, LDX, u3wb + SB6[p] * 128, 384, 128, lA, lW, acc);
    EPILOG_IDX;
#pragma unroll
    for (int m = 0; m < 4; ++m)
#pragma unroll
      for (int n = 0; n < 4; ++n)
#pragma unroll
        for (int j = 0; j < 4; ++j) {
          const int gc = cb + n * 16;
          u3f[(size_t)(m0 + rb + m * 16 + j) * 128 + gc] = acc[m][n][j] + u3b[gc];
        }
  }
}

__global__ __launch_bounds__(256) void u5_gemm(const bf16* __restrict__ rh3,
                                               const bf16* __restrict__ u5wb,
                                               const float* __restrict__ pre,
                                               const float* __restrict__ u3f,
                                               const float* __restrict__ h,
                                               const float* __restrict__ w3b,
                                               const float* __restrict__ w5b,
                                               const float* __restrict__ u5b,
                                               float* __restrict__ out) {
  __shared__ bf16 lA[4096];
  __shared__ bf16 lW[4096];
  const int m0 = blockIdx.y * 128;
  f32x4 acc[4][4];
  ACC_ZERO(acc);
  const bf16* Ab = rh3 + (size_t)m0 * 384;
#pragma unroll
  for (int p = 0; p < 6; ++p)
    gemm_seg(Ab + SA6[p] * 128, 384, u5wb + SB6[p] * 128, 384, 128, lA, lW, acc);
  EPILOG_IDX;
#pragma unroll
  for (int m = 0; m < 4; ++m)
#pragma unroll
    for (int n = 0; n < 4; ++n)
#pragma unroll
      for (int j = 0; j < 4; ++j) {
        const int gr = m0 + rb + m * 16 + j;
        const int gc = cb + n * 16;
        const float u5f = acc[m][n][j] + u5b[gc];
        const float z = sigmoidf_((pre[(size_t)gr * 384 + gc] + w3b[gc]) +
                                  u3f[(size_t)gr * 128 + gc]);
        const float hv = tanhf((pre[(size_t)gr * 384 + 256 + gc] + w5b[gc]) + u5f);
        const int bb = gr & 31, node = gr >> 5;
        const size_t hi = ((size_t)bb * 1024 + node) * 128 + gc;
        const float hh = h[hi];
        out[hi] = (1.f - z) * hh + z * hv;
      }
}

__global__ __launch_bounds__(256) void pack_h(const float* __restrict__ h,
                                              bf16* __restrict__ hN2,
                                              bf16* __restrict__ X2) {
  __shared__ unsigned int lds01[128][33];
  __shared__ unsigned short lds2[128][33];
  const int t = threadIdx.x;
  const int b = blockIdx.y;
  const int n0 = blockIdx.x * 32;
#pragma unroll
  for (int i = 0; i < 16; ++i) {
    const int idx = i * 256 + t;
    const int nl = idx >> 7, d = idx & 127;
    const float v = h[((size_t)b * 1024 + n0 + nl) * 128 + d];
    const bf16 l0 = (bf16)v;
    float r = v - (float)l0;
    const bf16 l1 = (bf16)r;
    r -= (float)l1;
    const bf16 l2 = (bf16)r;
    const size_t xr = ((size_t)(n0 + nl) * 32 + b) * LDX + 256 + d;
    X2[xr] = l0;
    X2[xr + 384] = l1;
    X2[xr + 768] = l2;
    lds01[d][nl] = (unsigned)bc16(l0) | ((unsigned)bc16(l1) << 16);
    lds2[d][nl] = bc16(l2);
  }
  __syncthreads();
#pragma unroll
  for (int i = 0; i < 16; ++i) {
    const int idx = i * 256 + t;
    const int d = idx >> 5, nl = idx & 31;
    const unsigned pk = lds01[d][nl];
    const unsigned short s2 = lds2[d][nl];
    bf16* row = hN2 + (size_t)(b * 128 + d) * LDH + n0 + nl;
    row[0] = bcbf((unsigned short)(pk & 0xffffu));
    row[1024] = bcbf((unsigned short)(pk >> 16));
    row[2048] = bcbf(s2);
  }
}

__global__ __launch_bounds__(256) void ew1(const float* __restrict__ pre,
                                           const float* __restrict__ u3f,
                                           const float* __restrict__ h,
                                           const float* __restrict__ w4b,
                                           bf16* __restrict__ rh3) {
  const int e4 = blockIdx.x * 256 + threadIdx.x;
  const int r = e4 >> 5;
  const int dq = (e4 & 31) * 4;
  const int b = r & 31, n = r >> 5;
  const f32x4 p = *(const f32x4*)(pre + (size_t)r * 384 + 128 + dq);
  const f32x4 uf = *(const f32x4*)(u3f + (size_t)r * 128 + dq);
  const f32x4 hh = *(const f32x4*)(h + ((size_t)b * 1024 + n) * 128 + dq);
  const f32x4 b4 = *(const f32x4*)(w4b + dq);
  bf16x4 o0, o1, o2;
#pragma unroll
  for (int j = 0; j < 4; ++j) {
    const float rr = sigmoidf_((p[j] + b4[j]) + uf[j]);
    const float v = rr * hh[j];
    o0[j] = (bf16)v;
    float res = v - (float)o0[j];
    o1[j] = (bf16)res;
    res -= (float)o1[j];
    o2[j] = (bf16)res;
  }
  *(bf16x4*)(rh3 + (size_t)r * 384 + dq) = o0;
  *(bf16x4*)(rh3 + (size_t)r * 384 + 128 + dq) = o1;
  *(bf16x4*)(rh3 + (size_t)r * 384 + 256 + dq) = o2;
}

__global__ __launch_bounds__(256) void split_adj(const float* __restrict__ src,
                                                 bf16* __restrict__ dst) {
  const int i = blockIdx.x * 256 + threadIdx.x;  // 1M
  const int r = i >> 10, c = i & 1023;
  const float v = src[i];
  const bf16 l0 = (bf16)v;
  float rr = v - (float)l0;
  const bf16 l1 = (bf16)rr;
  rr -= (float)l1;
  dst[(size_t)r * LDH + c] = l0;
  dst[(size_t)r * LDH + 1024 + c] = l1;
  dst[(size_t)r * LDH + 2048 + c] = (bf16)rr;
}

__global__ void build_wsm(const float* __restrict__ w3, const float* __restrict__ w4,
                          const float* __restrict__ w5, bf16* __restrict__ Wsm) {
  const int k = blockIdx.x * 128 + threadIdx.x;  // 0..255
  const int j = blockIdx.y;                      // 0..383
  float v;
  if (j < 128) v = w3[j * 256 + k];
  else if (j < 256) v = w4[(j - 128) * 256 + k];
  else v = w5[(j - 256) * 256 + k];
  const bf16 l0 = (bf16)v;
  float rr = v - (float)l0;
  const bf16 l1 = (bf16)rr;
  rr -= (float)l1;
  bf16* row = Wsm + (size_t)j * 768 + k;
  row[0] = l0;
  row[256] = l1;
  row[512] = (bf16)rr;
}

__global__ void build_uw(const float* __restrict__ u, bf16* __restrict__ dst) {
  const int i = blockIdx.x * 256 + threadIdx.x;  // 16384
  const int j = i >> 7, k = i & 127;
  const float v = u[i];
  const bf16 l0 = (bf16)v;
  float rr = v - (float)l0;
  const bf16 l1 = (bf16)rr;
  rr -= (float)l1;
  bf16* row = dst + (size_t)j * 384 + k;
  row[0] = l0;
  row[128] = l1;
  row[256] = (bf16)rr;
}

__global__ void sentinel(float* out, int n) {
  const int i = blockIdx.x * 256 + threadIdx.x;
  if (i < n) out[i] = 123456789.f;
}

extern "C" void kernel_launch(void* const* d_in, const int* in_sizes, int n_in,
                              void* d_out, int out_size, void* d_ws, size_t ws_size,
                              hipStream_t stream) {
  const float* input = (const float*)d_in[0];
  const float* Ain = (const float*)d_in[1];
  const float* Aout = (const float*)d_in[2];
  const float* w3w = (const float*)d_in[3];
  const float* w3b = (const float*)d_in[4];
  const float* u3w = (const float*)d_in[5];
  const float* u3b = (const float*)d_in[6];
  const float* w4w = (const float*)d_in[7];
  const float* w4b = (const float*)d_in[8];
  const float* w5w = (const float*)d_in[9];
  const float* w5b = (const float*)d_in[10];
  const float* u5wf = (const float*)d_in[11];
  const float* u5b = (const float*)d_in[12];
  // d_in[13] = time_step; fixed at 5 by the problem spec.

  char* ws = (char*)d_ws;
  size_t off = 0;
  auto alloc = [&](size_t bytes) -> void* {
    void* p = ws + off;
    off += (bytes + 255) & ~(size_t)255;
    return p;
  };
  bf16* A2 = (bf16*)alloc(2048ull * LDH * 2);   // 12.58 MB
  bf16* hN2 = (bf16*)alloc(4096ull * LDH * 2);  // 25.17 MB (rh3 overlay)
  bf16* X2 = (bf16*)alloc(32768ull * LDX * 2);  // 75.50 MB
  bf16* Wsm = (bf16*)alloc(384ull * 768 * 2);
  bf16* u3wb = (bf16*)alloc(128ull * 384 * 2);
  bf16* u5wb = (bf16*)alloc(128ull * 384 * 2);
  float* pre = (float*)alloc(32768ull * 384 * 4);  // 50.33 MB
  float* u3f = (float*)alloc(32768ull * 128 * 4);  // 16.78 MB
  bf16* rh3 = hN2;  // overlay: ew1 writes after adj8 read hN2; pack_h rewrites
  if (off > ws_size) {
    sentinel<<<dim3((out_size + 255) / 256), dim3(256), 0, stream>>>((float*)d_out, out_size);
    return;
  }

  split_adj<<<dim3(4096), dim3(256), 0, stream>>>(Ain, A2);
  split_adj<<<dim3(4096), dim3(256), 0, stream>>>(Aout, A2 + 1024ull * LDH);
  build_wsm<<<dim3(2, 384), dim3(128), 0, stream>>>(w3w, w4w, w5w, Wsm);
  build_uw<<<dim3(64), dim3(256), 0, stream>>>(u3w, u3wb);
  build_uw<<<dim3(64), dim3(256), 0, stream>>>(u5wf, u5wb);

  float* out = (float*)d_out;
  const float* h = input;
  for (int step = 0; step < 5; ++step) {
    pack_h<<<dim3(32, 32), dim3(256), 0, stream>>>(h, hN2, X2);
    // adjacency: M=2048(in|out), N=4096, virtual-K=6144, direct X2 split
    adj8<<<dim3(32, 8), dim3(512), 0, stream>>>(A2, hN2, X2);
    dense_gemm<<<dim3(4, 256), dim3(256), 0, stream>>>(X2, Wsm, u3wb, u3b, pre, u3f);
    ew1<<<dim3(4096), dim3(256), 0, stream>>>(pre, u3f, h, w4b, rh3);
    u5_gemm<<<dim3(1, 256), dim3(256), 0, stream>>>(rh3, u5wb, pre, u3f, h, w3b, w5b,
                                                    u5b, out);
    h = out;
  }
}

// Round 7
// 1142.703 us; speedup vs baseline: 1.2658x; 1.2658x over previous
//
#include <hip/hip_runtime.h>
#include <cstdint>
#include <cstddef>

// GGNN on MI355X. Round 7: numerics ≡ rounds 3-6 (3-limb bf16, corrections
// accumulated before the main product; main product's k-order unchanged).
// Adjacency rewritten as two-pass kk-outer product-sharing GEMM:
//   block 128x128, 4 waves (2Mx2N, wave tile 64x64), grid 16x32 = 512 = 2/CU
//   pass1 (BK=32): stage A l0-l2 + B l0-l2 once per kt (48KB, single-buffered),
//     hold 12 B-frags in regs, stream A by limb: products 11,10,02,01,20
//     -> 24 ds_read per 80 MFMA per wave (was 20 per 32)
//   pass2 (BK=64): main product 00 alone, 16 reads per 32 MFMA
//   slot-XOR swizzles (2-way max, free) staged via inverse-swizzled global src.
// Layouts unchanged:
//   A2  [2048: Ain|Aout][ l0|l1|l2 (1024 each) ]
//   hN2 [b*128+d][ l0|l1|l2 ]  (rh3 overlay)
//   X2  [n*32+b][ per-limb 384: m_in(128) m_out(128) h(128) ] x3  (LDX 1152)

typedef __bf16 bf16;
typedef __attribute__((ext_vector_type(8))) __bf16 bf16x8;
typedef __attribute__((ext_vector_type(4))) __bf16 bf16x4;
typedef __attribute__((ext_vector_type(4))) float f32x4;

#define LDX 1152
#define LDH 3072

// 6-product ascending schedule for the small GEMMs (unchanged)
static constexpr int SA6[6] = {1, 0, 2, 0, 1, 0};
static constexpr int SB6[6] = {1, 2, 0, 1, 0, 0};

static __device__ __forceinline__ void gload16(const void* g, void* l) {
  __builtin_amdgcn_global_load_lds(
      (const __attribute__((address_space(1))) void*)g,
      (__attribute__((address_space(3))) void*)l, 16, 0, 0);
}

static __device__ __forceinline__ float sigmoidf_(float x) {
  return 1.f / (1.f + expf(-x));
}

static __device__ __forceinline__ unsigned short bc16(bf16 x) {
  return __builtin_bit_cast(unsigned short, x);
}
static __device__ __forceinline__ bf16 bcbf(unsigned short x) {
  return __builtin_bit_cast(bf16, x);
}

// ================= adjacency: 128x128 block, 4 waves, two-pass kk-outer
__global__ __launch_bounds__(256, 2) void adj4(const bf16* __restrict__ A2,
                                               const bf16* __restrict__ hN2,
                                               bf16* __restrict__ X2) {
  // flat 48KB: A-region 12288 elems (3 planes of [128][32]), B-region same
  __shared__ bf16 lds[24576];
  bf16* ldsA = lds;
  bf16* ldsB = lds + 12288;
  const int t = threadIdx.x;
  const int wave = t >> 6, lane = t & 63;
  const int wr = wave >> 1, wn = wave & 1;  // 2M x 2N wave grid, 64x64 tiles
  const int m0 = blockIdx.y * 128;
  const int n0 = blockIdx.x * 128;

  f32x4 acc[4][4];
#pragma unroll
  for (int i = 0; i < 4; ++i)
#pragma unroll
    for (int j = 0; j < 4; ++j) acc[i][j] = {0.f, 0.f, 0.f, 0.f};

  const int frow = lane & 15;
  const int fk = lane >> 4;  // 0..3
  // pass1 frag slot (4 slots/row of 64B): swizzle f(r) = (r>>1)&3
  const int sl1 = fk ^ ((frow >> 1) & 3);
  // pass2 frag slots (8 slots/row of 128B): swizzle f(r) = r&7
  const int sl2a = fk ^ (frow & 7);
  const int sl2b = (4 + fk) ^ (frow & 7);
  // staging: inverse-swizzled global slots (g-independent, see derivation)
  const int gs1 = (t & 3) ^ ((t >> 3) & 3);
  const int gs2 = (t & 7) ^ ((t >> 3) & 7);

  // ---------------- pass 1: correction products {11,10,02,01,20}, BK=32
#define STAGE1(kt)                                                             \
  _Pragma("unroll") for (int lb = 0; lb < 3; ++lb) {                           \
    _Pragma("unroll") for (int g = 0; g < 2; ++g) {                            \
      const int row_ = g * 64 + (t >> 2);                                      \
      gload16(A2 + (size_t)(m0 + row_) * LDH + lb * 1024 + (kt) * 32 + gs1 * 8,\
              ldsA + lb * 4096 + g * 2048 + wave * 512);                       \
      gload16(hN2 + (size_t)(n0 + row_) * LDH + lb * 1024 + (kt) * 32 + gs1 * 8,\
              ldsB + lb * 4096 + g * 2048 + wave * 512);                       \
    }                                                                          \
  }

  for (int kt = 0; kt < 32; ++kt) {
    STAGE1(kt);
    asm volatile("s_waitcnt vmcnt(0)" ::: "memory");
    __builtin_amdgcn_s_barrier();
    asm volatile("" ::: "memory");

    bf16x8 bB[3][4];
#pragma unroll
    for (int lb = 0; lb < 3; ++lb)
#pragma unroll
      for (int nf = 0; nf < 4; ++nf)
        bB[lb][nf] =
            *(const bf16x8*)&ldsB[lb * 4096 + (wn * 64 + nf * 16 + frow) * 32 + sl1 * 8];

    bf16x8 aF[4];
    // group A-limb 1: products 1x1, 1x0
#pragma unroll
    for (int mf = 0; mf < 4; ++mf)
      aF[mf] = *(const bf16x8*)&ldsA[4096 + (wr * 64 + mf * 16 + frow) * 32 + sl1 * 8];
    __builtin_amdgcn_s_setprio(1);
#pragma unroll
    for (int mf = 0; mf < 4; ++mf)
#pragma unroll
      for (int nf = 0; nf < 4; ++nf)
        acc[mf][nf] = __builtin_amdgcn_mfma_f32_16x16x32_bf16(aF[mf], bB[1][nf],
                                                              acc[mf][nf], 0, 0, 0);
#pragma unroll
    for (int mf = 0; mf < 4; ++mf)
#pragma unroll
      for (int nf = 0; nf < 4; ++nf)
        acc[mf][nf] = __builtin_amdgcn_mfma_f32_16x16x32_bf16(aF[mf], bB[0][nf],
                                                              acc[mf][nf], 0, 0, 0);
    __builtin_amdgcn_s_setprio(0);
    // group A-limb 0: products 0x2, 0x1
#pragma unroll
    for (int mf = 0; mf < 4; ++mf)
      aF[mf] = *(const bf16x8*)&ldsA[(wr * 64 + mf * 16 + frow) * 32 + sl1 * 8];
    __builtin_amdgcn_s_setprio(1);
#pragma unroll
    for (int mf = 0; mf < 4; ++mf)
#pragma unroll
      for (int nf = 0; nf < 4; ++nf)
        acc[mf][nf] = __builtin_amdgcn_mfma_f32_16x16x32_bf16(aF[mf], bB[2][nf],
                                                              acc[mf][nf], 0, 0, 0);
#pragma unroll
    for (int mf = 0; mf < 4; ++mf)
#pragma unroll
      for (int nf = 0; nf < 4; ++nf)
        acc[mf][nf] = __builtin_amdgcn_mfma_f32_16x16x32_bf16(aF[mf], bB[1][nf],
                                                              acc[mf][nf], 0, 0, 0);
    __builtin_amdgcn_s_setprio(0);
    // group A-limb 2: product 2x0
#pragma unroll
    for (int mf = 0; mf < 4; ++mf)
      aF[mf] = *(const bf16x8*)&ldsA[8192 + (wr * 64 + mf * 16 + frow) * 32 + sl1 * 8];
    __builtin_amdgcn_s_setprio(1);
#pragma unroll
    for (int mf = 0; mf < 4; ++mf)
#pragma unroll
      for (int nf = 0; nf < 4; ++nf)
        acc[mf][nf] = __builtin_amdgcn_mfma_f32_16x16x32_bf16(aF[mf], bB[0][nf],
                                                              acc[mf][nf], 0, 0, 0);
    __builtin_amdgcn_s_setprio(0);

    asm volatile("" ::: "memory");
    __builtin_amdgcn_s_barrier();  // all reads done -> next kt may overwrite
  }
#undef STAGE1

  // ---------------- pass 2: main product 0x0, BK=64 ([128][64] tiles)
#define STAGE2(kt)                                                             \
  _Pragma("unroll") for (int g = 0; g < 4; ++g) {                              \
    const int row_ = g * 32 + (t >> 3);                                        \
    gload16(A2 + (size_t)(m0 + row_) * LDH + (kt) * 64 + gs2 * 8,              \
            ldsA + g * 2048 + wave * 512);                                     \
    gload16(hN2 + (size_t)(n0 + row_) * LDH + (kt) * 64 + gs2 * 8,             \
            ldsB + g * 2048 + wave * 512);                                     \
  }

  for (int kt = 0; kt < 16; ++kt) {
    STAGE2(kt);
    asm volatile("s_waitcnt vmcnt(0)" ::: "memory");
    __builtin_amdgcn_s_barrier();
    asm volatile("" ::: "memory");

    bf16x8 a2[4][2], b2[4][2];
#pragma unroll
    for (int mf = 0; mf < 4; ++mf) {
      const int row = wr * 64 + mf * 16 + frow;
      a2[mf][0] = *(const bf16x8*)&ldsA[row * 64 + sl2a * 8];
      a2[mf][1] = *(const bf16x8*)&ldsA[row * 64 + sl2b * 8];
    }
#pragma unroll
    for (int nf = 0; nf < 4; ++nf) {
      const int row = wn * 64 + nf * 16 + frow;
      b2[nf][0] = *(const bf16x8*)&ldsB[row * 64 + sl2a * 8];
      b2[nf][1] = *(const bf16x8*)&ldsB[row * 64 + sl2b * 8];
    }
    __builtin_amdgcn_s_setprio(1);
#pragma unroll
    for (int ks = 0; ks < 2; ++ks)  // k ascending per acc element
#pragma unroll
      for (int mf = 0; mf < 4; ++mf)
#pragma unroll
        for (int nf = 0; nf < 4; ++nf)
          acc[mf][nf] = __builtin_amdgcn_mfma_f32_16x16x32_bf16(a2[mf][ks], b2[nf][ks],
                                                                acc[mf][nf], 0, 0, 0);
    __builtin_amdgcn_s_setprio(0);

    asm volatile("" ::: "memory");
    __builtin_amdgcn_s_barrier();
  }
#undef STAGE2

  // epilogue: C/D layout col=lane&15, row=(lane>>4)*4+j; 3-limb X2 split
  const int rb = m0 + wr * 64 + (lane >> 4) * 4;
  const int cb = n0 + wn * 64 + frow;
#pragma unroll
  for (int mf = 0; mf < 4; ++mf)
#pragma unroll
    for (int nf = 0; nf < 4; ++nf)
#pragma unroll
      for (int j = 0; j < 4; ++j) {
        const int gr = rb + mf * 16 + j;
        const int gc = cb + nf * 16;
        const float v = acc[mf][nf][j];
        const int node = gr & 1023;
        const int coff = (gr >> 10) * 128;  // 0: m_in, 128: m_out
        const int bb = gc >> 7, d = gc & 127;
        bf16* px = X2 + ((size_t)node * 32 + bb) * LDX + coff + d;
        const bf16 l0 = (bf16)v;
        float r = v - (float)l0;
        const bf16 l1 = (bf16)r;
        r -= (float)l1;
        px[0] = l0;
        px[384] = l1;
        px[768] = (bf16)r;
      }
}

// ================= (unchanged below: dense/u5/pack/ew/init)
static __device__ __forceinline__ void gemm_seg(const bf16* __restrict__ Ao, int lda,
                                                const bf16* __restrict__ Wo, int ldw,
                                                int Kseg, bf16* lA, bf16* lW,
                                                f32x4 (&acc)[4][4]) {
  const int t = threadIdx.x;
  const int wave = t >> 6, lane = t & 63;
  const int wr = wave >> 1, wc = wave & 1;
  const int srow = t >> 2, scol = (t & 3) * 8;
  const int frow = lane & 15, kfr = (lane >> 4) * 8;
  for (int kk = 0; kk < Kseg; kk += 32) {
    const bf16* ga = Ao + (size_t)srow * lda + kk + scol;
    bf16* la = lA + wave * 512;
    gload16(ga, la);
    gload16(ga + (size_t)64 * lda, la + 2048);
    const bf16* gw = Wo + (size_t)srow * ldw + kk + scol;
    bf16* lw = lW + wave * 512;
    gload16(gw, lw);
    gload16(gw + (size_t)64 * ldw, lw + 2048);
    __syncthreads();
    bf16x8 af[4], wf[4];
#pragma unroll
    for (int m = 0; m < 4; ++m)
      af[m] = *(const bf16x8*)(lA + (wr * 64 + m * 16 + frow) * 32 + kfr);
#pragma unroll
    for (int n = 0; n < 4; ++n)
      wf[n] = *(const bf16x8*)(lW + (wc * 64 + n * 16 + frow) * 32 + kfr);
#pragma unroll
    for (int m = 0; m < 4; ++m)
#pragma unroll
      for (int n = 0; n < 4; ++n)
        acc[m][n] = __builtin_amdgcn_mfma_f32_16x16x32_bf16(af[m], wf[n], acc[m][n], 0, 0, 0);
    __syncthreads();
  }
}

#define ACC_ZERO(acc)                          \
  _Pragma("unroll") for (int i = 0; i < 4; ++i) \
  _Pragma("unroll") for (int j = 0; j < 4; ++j) acc[i][j] = {0.f, 0.f, 0.f, 0.f};

#define EPILOG_IDX                                          \
  const int t = threadIdx.x;                                \
  const int wave = t >> 6, lane = t & 63;                   \
  const int rb = (wave >> 1) * 64 + (lane >> 4) * 4;        \
  const int cb = (wave & 1) * 64 + (lane & 15);

__global__ __launch_bounds__(256) void dense_gemm(const bf16* __restrict__ X2,
                                                  const bf16* __restrict__ Wsm,
                                                  const bf16* __restrict__ u3wb,
                                                  const float* __restrict__ u3b,
                                                  float* __restrict__ pre,
                                                  float* __restrict__ u3f) {
  __shared__ bf16 lA[4096];
  __shared__ bf16 lW[4096];
  const int m0 = blockIdx.y * 128;
  const int bx = blockIdx.x;
  f32x4 acc[4][4];
  ACC_ZERO(acc);
  if (bx < 3) {
    const bf16* Ab = X2 + (size_t)m0 * LDX;
    const bf16* Wb = Wsm + (size_t)(bx * 128) * 768;
#pragma unroll
    for (int p = 0; p < 6; ++p)
      gemm_seg(Ab + SA6[p] * 384, LDX, Wb + SB6[p] * 256, 768, 256, lA, lW, acc);
    EPILOG_IDX;
#pragma unroll
    for (int m = 0; m < 4; ++m)
#pragma unroll
      for (int n = 0; n < 4; ++n)
#pragma unroll
        for (int j = 0; j < 4; ++j)
          pre[(size_t)(m0 + rb + m * 16 + j) * 384 + bx * 128 + cb + n * 16] = acc[m][n][j];
  } else {
    const bf16* Ab = X2 + (size_t)m0 * LDX + 256;
#pragma unroll
    for (int p = 0; p < 6; ++p)
      gemm_seg(Ab + SA6[p] * 384, LDX, u3wb + SB6[p] * 128, 384, 128, lA, lW, acc);
    EPILOG_IDX;
#pragma unroll
    for (int m = 0; m < 4; ++m)
#pragma unroll
      for (int n = 0; n < 4; ++n)
#pragma unroll
        for (int j = 0; j < 4; ++j) {
          const int gc = cb + n * 16;
          u3f[(size_t)(m0 + rb + m * 16 + j) * 128 + gc] = acc[m][n][j] + u3b[gc];
        }
  }
}

__global__ __launch_bounds__(256) void u5_gemm(const bf16* __restrict__ rh3,
                                               const bf16* __restrict__ u5wb,
                                               const float* __restrict__ pre,
                                               const float* __restrict__ u3f,
                                               const float* __restrict__ h,
                                               const float* __restrict__ w3b,
                                               const float* __restrict__ w5b,
                                               const float* __restrict__ u5b,
                                               float* __restrict__ out) {
  __shared__ bf16 lA[4096];
  __shared__ bf16 lW[4096];
  const int m0 = blockIdx.y * 128;
  f32x4 acc[4][4];
  ACC_ZERO(acc);
  const bf16* Ab = rh3 + (size_t)m0 * 384;
#pragma unroll
  for (int p = 0; p < 6; ++p)
    gemm_seg(Ab + SA6[p] * 128, 384, u5wb + SB6[p] * 128, 384, 128, lA, lW, acc);
  EPILOG_IDX;
#pragma unroll
  for (int m = 0; m < 4; ++m)
#pragma unroll
    for (int n = 0; n < 4; ++n)
#pragma unroll
      for (int j = 0; j < 4; ++j) {
        const int gr = m0 + rb + m * 16 + j;
        const int gc = cb + n * 16;
        const float u5f = acc[m][n][j] + u5b[gc];
        const float z = sigmoidf_((pre[(size_t)gr * 384 + gc] + w3b[gc]) +
                                  u3f[(size_t)gr * 128 + gc]);
        const float hv = tanhf((pre[(size_t)gr * 384 + 256 + gc] + w5b[gc]) + u5f);
        const int bb = gr & 31, node = gr >> 5;
        const size_t hi = ((size_t)bb * 1024 + node) * 128 + gc;
        const float hh = h[hi];
        out[hi] = (1.f - z) * hh + z * hv;
      }
}

__global__ __launch_bounds__(256) void pack_h(const float* __restrict__ h,
                                              bf16* __restrict__ hN2,
                                              bf16* __restrict__ X2) {
  __shared__ unsigned int lds01[128][33];
  __shared__ unsigned short lds2[128][33];
  const int t = threadIdx.x;
  const int b = blockIdx.y;
  const int n0 = blockIdx.x * 32;
#pragma unroll
  for (int i = 0; i < 16; ++i) {
    const int idx = i * 256 + t;
    const int nl = idx >> 7, d = idx & 127;
    const float v = h[((size_t)b * 1024 + n0 + nl) * 128 + d];
    const bf16 l0 = (bf16)v;
    float r = v - (float)l0;
    const bf16 l1 = (bf16)r;
    r -= (float)l1;
    const bf16 l2 = (bf16)r;
    const size_t xr = ((size_t)(n0 + nl) * 32 + b) * LDX + 256 + d;
    X2[xr] = l0;
    X2[xr + 384] = l1;
    X2[xr + 768] = l2;
    lds01[d][nl] = (unsigned)bc16(l0) | ((unsigned)bc16(l1) << 16);
    lds2[d][nl] = bc16(l2);
  }
  __syncthreads();
#pragma unroll
  for (int i = 0; i < 16; ++i) {
    const int idx = i * 256 + t;
    const int d = idx >> 5, nl = idx & 31;
    const unsigned pk = lds01[d][nl];
    const unsigned short s2 = lds2[d][nl];
    bf16* row = hN2 + (size_t)(b * 128 + d) * LDH + n0 + nl;
    row[0] = bcbf((unsigned short)(pk & 0xffffu));
    row[1024] = bcbf((unsigned short)(pk >> 16));
    row[2048] = bcbf(s2);
  }
}

__global__ __launch_bounds__(256) void ew1(const float* __restrict__ pre,
                                           const float* __restrict__ u3f,
                                           const float* __restrict__ h,
                                           const float* __restrict__ w4b,
                                           bf16* __restrict__ rh3) {
  const int e4 = blockIdx.x * 256 + threadIdx.x;
  const int r = e4 >> 5;
  const int dq = (e4 & 31) * 4;
  const int b = r & 31, n = r >> 5;
  const f32x4 p = *(const f32x4*)(pre + (size_t)r * 384 + 128 + dq);
  const f32x4 uf = *(const f32x4*)(u3f + (size_t)r * 128 + dq);
  const f32x4 hh = *(const f32x4*)(h + ((size_t)b * 1024 + n) * 128 + dq);
  const f32x4 b4 = *(const f32x4*)(w4b + dq);
  bf16x4 o0, o1, o2;
#pragma unroll
  for (int j = 0; j < 4; ++j) {
    const float rr = sigmoidf_((p[j] + b4[j]) + uf[j]);
    const float v = rr * hh[j];
    o0[j] = (bf16)v;
    float res = v - (float)o0[j];
    o1[j] = (bf16)res;
    res -= (float)o1[j];
    o2[j] = (bf16)res;
  }
  *(bf16x4*)(rh3 + (size_t)r * 384 + dq) = o0;
  *(bf16x4*)(rh3 + (size_t)r * 384 + 128 + dq) = o1;
  *(bf16x4*)(rh3 + (size_t)r * 384 + 256 + dq) = o2;
}

__global__ __launch_bounds__(256) void split_adj(const float* __restrict__ src,
                                                 bf16* __restrict__ dst) {
  const int i = blockIdx.x * 256 + threadIdx.x;  // 1M
  const int r = i >> 10, c = i & 1023;
  const float v = src[i];
  const bf16 l0 = (bf16)v;
  float rr = v - (float)l0;
  const bf16 l1 = (bf16)rr;
  rr -= (float)l1;
  dst[(size_t)r * LDH + c] = l0;
  dst[(size_t)r * LDH + 1024 + c] = l1;
  dst[(size_t)r * LDH + 2048 + c] = (bf16)rr;
}

__global__ void build_wsm(const float* __restrict__ w3, const float* __restrict__ w4,
                          const float* __restrict__ w5, bf16* __restrict__ Wsm) {
  const int k = blockIdx.x * 128 + threadIdx.x;  // 0..255
  const int j = blockIdx.y;                      // 0..383
  float v;
  if (j < 128) v = w3[j * 256 + k];
  else if (j < 256) v = w4[(j - 128) * 256 + k];
  else v = w5[(j - 256) * 256 + k];
  const bf16 l0 = (bf16)v;
  float rr = v - (float)l0;
  const bf16 l1 = (bf16)rr;
  rr -= (float)l1;
  bf16* row = Wsm + (size_t)j * 768 + k;
  row[0] = l0;
  row[256] = l1;
  row[512] = (bf16)rr;
}

__global__ void build_uw(const float* __restrict__ u, bf16* __restrict__ dst) {
  const int i = blockIdx.x * 256 + threadIdx.x;  // 16384
  const int j = i >> 7, k = i & 127;
  const float v = u[i];
  const bf16 l0 = (bf16)v;
  float rr = v - (float)l0;
  const bf16 l1 = (bf16)rr;
  rr -= (float)l1;
  bf16* row = dst + (size_t)j * 384 + k;
  row[0] = l0;
  row[128] = l1;
  row[256] = (bf16)rr;
}

__global__ void sentinel(float* out, int n) {
  const int i = blockIdx.x * 256 + threadIdx.x;
  if (i < n) out[i] = 123456789.f;
}

extern "C" void kernel_launch(void* const* d_in, const int* in_sizes, int n_in,
                              void* d_out, int out_size, void* d_ws, size_t ws_size,
                              hipStream_t stream) {
  const float* input = (const float*)d_in[0];
  const float* Ain = (const float*)d_in[1];
  const float* Aout = (const float*)d_in[2];
  const float* w3w = (const float*)d_in[3];
  const float* w3b = (const float*)d_in[4];
  const float* u3w = (const float*)d_in[5];
  const float* u3b = (const float*)d_in[6];
  const float* w4w = (const float*)d_in[7];
  const float* w4b = (const float*)d_in[8];
  const float* w5w = (const float*)d_in[9];
  const float* w5b = (const float*)d_in[10];
  const float* u5wf = (const float*)d_in[11];
  const float* u5b = (const float*)d_in[12];
  // d_in[13] = time_step; fixed at 5 by the problem spec.

  char* ws = (char*)d_ws;
  size_t off = 0;
  auto alloc = [&](size_t bytes) -> void* {
    void* p = ws + off;
    off += (bytes + 255) & ~(size_t)255;
    return p;
  };
  bf16* A2 = (bf16*)alloc(2048ull * LDH * 2);   // 12.58 MB
  bf16* hN2 = (bf16*)alloc(4096ull * LDH * 2);  // 25.17 MB (rh3 overlay)
  bf16* X2 = (bf16*)alloc(32768ull * LDX * 2);  // 75.50 MB
  bf16* Wsm = (bf16*)alloc(384ull * 768 * 2);
  bf16* u3wb = (bf16*)alloc(128ull * 384 * 2);
  bf16* u5wb = (bf16*)alloc(128ull * 384 * 2);
  float* pre = (float*)alloc(32768ull * 384 * 4);  // 50.33 MB
  float* u3f = (float*)alloc(32768ull * 128 * 4);  // 16.78 MB
  bf16* rh3 = hN2;  // overlay: ew1 writes after adj4 read hN2; pack_h rewrites
  if (off > ws_size) {
    sentinel<<<dim3((out_size + 255) / 256), dim3(256), 0, stream>>>((float*)d_out, out_size);
    return;
  }

  split_adj<<<dim3(4096), dim3(256), 0, stream>>>(Ain, A2);
  split_adj<<<dim3(4096), dim3(256), 0, stream>>>(Aout, A2 + 1024ull * LDH);
  build_wsm<<<dim3(2, 384), dim3(128), 0, stream>>>(w3w, w4w, w5w, Wsm);
  build_uw<<<dim3(64), dim3(256), 0, stream>>>(u3w, u3wb);
  build_uw<<<dim3(64), dim3(256), 0, stream>>>(u5wf, u5wb);

  float* out = (float*)d_out;
  const float* h = input;
  for (int step = 0; step < 5; ++step) {
    pack_h<<<dim3(32, 32), dim3(256), 0, stream>>>(h, hN2, X2);
    // adjacency: M=2048(in|out), N=4096, two-pass kk-outer, direct X2 split
    adj4<<<dim3(32, 16), dim3(256), 0, stream>>>(A2, hN2, X2);
    dense_gemm<<<dim3(4, 256), dim3(256), 0, stream>>>(X2, Wsm, u3wb, u3b, pre, u3f);
    ew1<<<dim3(4096), dim3(256), 0, stream>>>(pre, u3f, h, w4b, rh3);
    u5_gemm<<<dim3(1, 256), dim3(256), 0, stream>>>(rh3, u5wb, pre, u3f, h, w3b, w5b,
                                                    u5b, out);
    h = out;
  }
}

// Round 8
// 1086.963 us; speedup vs baseline: 1.3307x; 1.0513x over previous
//
#include <hip/hip_runtime.h>
#include <cstdint>
#include <cstddef>

// GGNN on MI355X. Round 8: numerics ≡ round 7 (3-limb bf16, corrections first
// {11,10,02,01,20} then main {00}; fp32-equivalent; absmax 0.015625).
// The r7 adj4 structure (kk-outer product-sharing, 64x64 wave tiles, 2-barrier
// single-buffer, slot-XOR swizzle) is factored into gemm2p() and applied to
// ALL GEMMs: adjacency (unchanged codegen), dense W/u3, and u5 (+fused ew2).
// Layouts unchanged:
//   A2  [2048: Ain|Aout][ l0|l1|l2 (1024 each) ]
//   hN2 [b*128+d][ l0|l1|l2 ]  (rh3 overlay)
//   X2  [n*32+b][ per-limb 384: m_in(128) m_out(128) h(128) ] x3  (LDX 1152)
//   Wsm [384: w3|w4|w5][ per-limb 256 ]; u3wb/u5wb [128][ per-limb 128 ]

typedef __bf16 bf16;
typedef __attribute__((ext_vector_type(8))) __bf16 bf16x8;
typedef __attribute__((ext_vector_type(4))) __bf16 bf16x4;
typedef __attribute__((ext_vector_type(4))) float f32x4;

#define LDX 1152
#define LDH 3072

static __device__ __forceinline__ void gload16(const void* g, void* l) {
  __builtin_amdgcn_global_load_lds(
      (const __attribute__((address_space(1))) void*)g,
      (__attribute__((address_space(3))) void*)l, 16, 0, 0);
}

static __device__ __forceinline__ float sigmoidf_(float x) {
  return 1.f / (1.f + expf(-x));
}

static __device__ __forceinline__ unsigned short bc16(bf16 x) {
  return __builtin_bit_cast(unsigned short, x);
}
static __device__ __forceinline__ bf16 bcbf(unsigned short x) {
  return __builtin_bit_cast(bf16, x);
}

// ======== two-pass product-sharing 128x128-tile GEMM core (r7-verified) ========
// A: 128 rows, row stride lda, limb l at column (abase + l*aLS + k), k in [0,K)
// B: 128 rows, row stride ldb, limb l at column (l*bLS + k)
// pass1 (BK=32, nkt1=K/32): stage 3 A-limbs + 3 B-limbs once, compute the 5
//   correction products {1x1, 1x0, 0x2, 0x1, 2x0}; pass2 (BK=64, nkt2=K/64):
//   main product {0x0}, k ascending. acc[4][4] per wave (64x64 wave tile,
//   4 waves as 2Mx2N). lds must be 24576 bf16 (48KB).
static __device__ __forceinline__ void gemm2p(const bf16* __restrict__ A, int lda,
                                              int aLS, int abase,
                                              const bf16* __restrict__ B, int ldb,
                                              int bLS, int nkt1, int nkt2,
                                              bf16* lds, f32x4 (&acc)[4][4]) {
  bf16* ldsA = lds;
  bf16* ldsB = lds + 12288;
  const int t = threadIdx.x;
  const int wave = t >> 6, lane = t & 63;
  const int wr = wave >> 1, wn = wave & 1;
  const int frow = lane & 15;
  const int fk = lane >> 4;  // 0..3
  const int sl1 = fk ^ ((frow >> 1) & 3);     // pass1 frag slot (4x16B/row)
  const int sl2a = fk ^ (frow & 7);           // pass2 frag slots (8x16B/row)
  const int sl2b = (4 + fk) ^ (frow & 7);
  const int gs1 = (t & 3) ^ ((t >> 3) & 3);   // inverse-swizzled global slots
  const int gs2 = (t & 7) ^ ((t >> 3) & 7);

  // ---------------- pass 1: corrections, BK=32
  for (int kt = 0; kt < nkt1; ++kt) {
#pragma unroll
    for (int lb = 0; lb < 3; ++lb)
#pragma unroll
      for (int g = 0; g < 2; ++g) {
        const int row_ = g * 64 + (t >> 2);
        gload16(A + (size_t)row_ * lda + abase + lb * aLS + kt * 32 + gs1 * 8,
                ldsA + lb * 4096 + g * 2048 + wave * 512);
        gload16(B + (size_t)row_ * ldb + lb * bLS + kt * 32 + gs1 * 8,
                ldsB + lb * 4096 + g * 2048 + wave * 512);
      }
    asm volatile("s_waitcnt vmcnt(0)" ::: "memory");
    __builtin_amdgcn_s_barrier();
    asm volatile("" ::: "memory");

    bf16x8 bB[3][4];
#pragma unroll
    for (int lb = 0; lb < 3; ++lb)
#pragma unroll
      for (int nf = 0; nf < 4; ++nf)
        bB[lb][nf] =
            *(const bf16x8*)&ldsB[lb * 4096 + (wn * 64 + nf * 16 + frow) * 32 + sl1 * 8];

    bf16x8 aF[4];
    // A-limb 1: products 1x1, 1x0
#pragma unroll
    for (int mf = 0; mf < 4; ++mf)
      aF[mf] = *(const bf16x8*)&ldsA[4096 + (wr * 64 + mf * 16 + frow) * 32 + sl1 * 8];
    __builtin_amdgcn_s_setprio(1);
#pragma unroll
    for (int mf = 0; mf < 4; ++mf)
#pragma unroll
      for (int nf = 0; nf < 4; ++nf)
        acc[mf][nf] = __builtin_amdgcn_mfma_f32_16x16x32_bf16(aF[mf], bB[1][nf],
                                                              acc[mf][nf], 0, 0, 0);
#pragma unroll
    for (int mf = 0; mf < 4; ++mf)
#pragma unroll
      for (int nf = 0; nf < 4; ++nf)
        acc[mf][nf] = __builtin_amdgcn_mfma_f32_16x16x32_bf16(aF[mf], bB[0][nf],
                                                              acc[mf][nf], 0, 0, 0);
    __builtin_amdgcn_s_setprio(0);
    // A-limb 0: products 0x2, 0x1
#pragma unroll
    for (int mf = 0; mf < 4; ++mf)
      aF[mf] = *(const bf16x8*)&ldsA[(wr * 64 + mf * 16 + frow) * 32 + sl1 * 8];
    __builtin_amdgcn_s_setprio(1);
#pragma unroll
    for (int mf = 0; mf < 4; ++mf)
#pragma unroll
      for (int nf = 0; nf < 4; ++nf)
        acc[mf][nf] = __builtin_amdgcn_mfma_f32_16x16x32_bf16(aF[mf], bB[2][nf],
                                                              acc[mf][nf], 0, 0, 0);
#pragma unroll
    for (int mf = 0; mf < 4; ++mf)
#pragma unroll
      for (int nf = 0; nf < 4; ++nf)
        acc[mf][nf] = __builtin_amdgcn_mfma_f32_16x16x32_bf16(aF[mf], bB[1][nf],
                                                              acc[mf][nf], 0, 0, 0);
    __builtin_amdgcn_s_setprio(0);
    // A-limb 2: product 2x0
#pragma unroll
    for (int mf = 0; mf < 4; ++mf)
      aF[mf] = *(const bf16x8*)&ldsA[8192 + (wr * 64 + mf * 16 + frow) * 32 + sl1 * 8];
    __builtin_amdgcn_s_setprio(1);
#pragma unroll
    for (int mf = 0; mf < 4; ++mf)
#pragma unroll
      for (int nf = 0; nf < 4; ++nf)
        acc[mf][nf] = __builtin_amdgcn_mfma_f32_16x16x32_bf16(aF[mf], bB[0][nf],
                                                              acc[mf][nf], 0, 0, 0);
    __builtin_amdgcn_s_setprio(0);

    asm volatile("" ::: "memory");
    __builtin_amdgcn_s_barrier();  // all reads done -> next kt may overwrite
  }

  // ---------------- pass 2: main product, BK=64
  for (int kt = 0; kt < nkt2; ++kt) {
#pragma unroll
    for (int g = 0; g < 4; ++g) {
      const int row_ = g * 32 + (t >> 3);
      gload16(A + (size_t)row_ * lda + abase + kt * 64 + gs2 * 8,
              ldsA + g * 2048 + wave * 512);
      gload16(B + (size_t)row_ * ldb + kt * 64 + gs2 * 8,
              ldsB + g * 2048 + wave * 512);
    }
    asm volatile("s_waitcnt vmcnt(0)" ::: "memory");
    __builtin_amdgcn_s_barrier();
    asm volatile("" ::: "memory");

    bf16x8 a2[4][2], b2[4][2];
#pragma unroll
    for (int mf = 0; mf < 4; ++mf) {
      const int row = wr * 64 + mf * 16 + frow;
      a2[mf][0] = *(const bf16x8*)&ldsA[row * 64 + sl2a * 8];
      a2[mf][1] = *(const bf16x8*)&ldsA[row * 64 + sl2b * 8];
    }
#pragma unroll
    for (int nf = 0; nf < 4; ++nf) {
      const int row = wn * 64 + nf * 16 + frow;
      b2[nf][0] = *(const bf16x8*)&ldsB[row * 64 + sl2a * 8];
      b2[nf][1] = *(const bf16x8*)&ldsB[row * 64 + sl2b * 8];
    }
    __builtin_amdgcn_s_setprio(1);
#pragma unroll
    for (int ks = 0; ks < 2; ++ks)  // k ascending per acc element
#pragma unroll
      for (int mf = 0; mf < 4; ++mf)
#pragma unroll
        for (int nf = 0; nf < 4; ++nf)
          acc[mf][nf] = __builtin_amdgcn_mfma_f32_16x16x32_bf16(a2[mf][ks], b2[nf][ks],
                                                                acc[mf][nf], 0, 0, 0);
    __builtin_amdgcn_s_setprio(0);

    asm volatile("" ::: "memory");
    __builtin_amdgcn_s_barrier();
  }
}

#define ACC_ZERO(acc)                          \
  _Pragma("unroll") for (int i = 0; i < 4; ++i) \
  _Pragma("unroll") for (int j = 0; j < 4; ++j) acc[i][j] = {0.f, 0.f, 0.f, 0.f};

// ================= adjacency (r7 adj4 via helper; codegen-identical)
__global__ __launch_bounds__(256, 2) void adj4(const bf16* __restrict__ A2,
                                               const bf16* __restrict__ hN2,
                                               bf16* __restrict__ X2) {
  __shared__ bf16 lds[24576];
  const int m0 = blockIdx.y * 128;
  const int n0 = blockIdx.x * 128;
  f32x4 acc[4][4];
  ACC_ZERO(acc);
  gemm2p(A2 + (size_t)m0 * LDH, LDH, 1024, 0, hN2 + (size_t)n0 * LDH, LDH, 1024,
         32, 16, lds, acc);

  const int lane = threadIdx.x & 63, wave = threadIdx.x >> 6;
  const int rb = m0 + (wave >> 1) * 64 + (lane >> 4) * 4;
  const int cb = n0 + (wave & 1) * 64 + (lane & 15);
#pragma unroll
  for (int mf = 0; mf < 4; ++mf)
#pragma unroll
    for (int nf = 0; nf < 4; ++nf)
#pragma unroll
      for (int j = 0; j < 4; ++j) {
        const int gr = rb + mf * 16 + j;
        const int gc = cb + nf * 16;
        const float v = acc[mf][nf][j];
        const int node = gr & 1023;
        const int coff = (gr >> 10) * 128;  // 0: m_in, 128: m_out
        const int bb = gc >> 7, d = gc & 127;
        bf16* px = X2 + ((size_t)node * 32 + bb) * LDX + coff + d;
        const bf16 l0 = (bf16)v;
        float r = v - (float)l0;
        const bf16 l1 = (bf16)r;
        r -= (float)l1;
        px[0] = l0;
        px[384] = l1;
        px[768] = (bf16)r;
      }
}

// ================= dense: bx<3 -> pre[.][bx*128..]; bx==3 -> u3f (+u3b)
__global__ __launch_bounds__(256, 2) void dense4(const bf16* __restrict__ X2,
                                                 const bf16* __restrict__ Wsm,
                                                 const bf16* __restrict__ u3wb,
                                                 const float* __restrict__ u3b,
                                                 float* __restrict__ pre,
                                                 float* __restrict__ u3f) {
  __shared__ bf16 lds[24576];
  const int m0 = blockIdx.y * 128;
  const int bx = blockIdx.x;
  f32x4 acc[4][4];
  ACC_ZERO(acc);
  const int lane = threadIdx.x & 63, wave = threadIdx.x >> 6;
  const int rb = m0 + (wave >> 1) * 64 + (lane >> 4) * 4;
  const int cb = (wave & 1) * 64 + (lane & 15);
  if (bx < 3) {
    gemm2p(X2 + (size_t)m0 * LDX, LDX, 384, 0, Wsm + (size_t)bx * 128 * 768, 768, 256,
           8, 4, lds, acc);
#pragma unroll
    for (int mf = 0; mf < 4; ++mf)
#pragma unroll
      for (int nf = 0; nf < 4; ++nf)
#pragma unroll
        for (int j = 0; j < 4; ++j)
          pre[(size_t)(rb + mf * 16 + j) * 384 + bx * 128 + cb + nf * 16] =
              acc[mf][nf][j];
  } else {
    gemm2p(X2 + (size_t)m0 * LDX, LDX, 384, 256, u3wb, 384, 128, 4, 2, lds, acc);
#pragma unroll
    for (int mf = 0; mf < 4; ++mf)
#pragma unroll
      for (int nf = 0; nf < 4; ++nf)
#pragma unroll
        for (int j = 0; j < 4; ++j) {
          const int gc = cb + nf * 16;
          // np: u3 = (h@u3w^T) + u3b, rounded once
          u3f[(size_t)(rb + mf * 16 + j) * 128 + gc] = acc[mf][nf][j] + u3b[gc];
        }
  }
}

// ================= u5 GEMM + fused ew2 epilogue (z, hv, h' -> out)
__global__ __launch_bounds__(256, 2) void u5g(const bf16* __restrict__ rh3,
                                              const bf16* __restrict__ u5wb,
                                              const float* __restrict__ pre,
                                              const float* __restrict__ u3f,
                                              const float* __restrict__ h,
                                              const float* __restrict__ w3b,
                                              const float* __restrict__ w5b,
                                              const float* __restrict__ u5b,
                                              float* __restrict__ out) {
  __shared__ bf16 lds[24576];
  const int m0 = blockIdx.x * 128;
  f32x4 acc[4][4];
  ACC_ZERO(acc);
  gemm2p(rh3 + (size_t)m0 * 384, 384, 128, 0, u5wb, 384, 128, 4, 2, lds, acc);

  const int lane = threadIdx.x & 63, wave = threadIdx.x >> 6;
  const int rb = m0 + (wave >> 1) * 64 + (lane >> 4) * 4;
  const int cb = (wave & 1) * 64 + (lane & 15);
#pragma unroll
  for (int mf = 0; mf < 4; ++mf)
#pragma unroll
    for (int nf = 0; nf < 4; ++nf)
#pragma unroll
      for (int j = 0; j < 4; ++j) {
        const int gr = rb + mf * 16 + j;
        const int gc = cb + nf * 16;
        const float u5f = acc[mf][nf][j] + u5b[gc];  // np: U5 + u5b
        const float z = sigmoidf_((pre[(size_t)gr * 384 + gc] + w3b[gc]) +
                                  u3f[(size_t)gr * 128 + gc]);
        const float hv = tanhf((pre[(size_t)gr * 384 + 256 + gc] + w5b[gc]) + u5f);
        const int bb = gr & 31, node = gr >> 5;
        const size_t hi = ((size_t)bb * 1024 + node) * 128 + gc;
        const float hh = h[hi];
        out[hi] = (1.f - z) * hh + z * hv;  // np: (1-z)*h + z*hv
      }
}

// ================= pack h (fp32 [B][N][D]) -> hN2 3-limb + X2 h-columns 3-limb
__global__ __launch_bounds__(256) void pack_h(const float* __restrict__ h,
                                              bf16* __restrict__ hN2,
                                              bf16* __restrict__ X2) {
  __shared__ unsigned int lds01[128][33];
  __shared__ unsigned short lds2[128][33];
  const int t = threadIdx.x;
  const int b = blockIdx.y;
  const int n0 = blockIdx.x * 32;
#pragma unroll
  for (int i = 0; i < 16; ++i) {
    const int idx = i * 256 + t;
    const int nl = idx >> 7, d = idx & 127;
    const float v = h[((size_t)b * 1024 + n0 + nl) * 128 + d];
    const bf16 l0 = (bf16)v;
    float r = v - (float)l0;
    const bf16 l1 = (bf16)r;
    r -= (float)l1;
    const bf16 l2 = (bf16)r;
    const size_t xr = ((size_t)(n0 + nl) * 32 + b) * LDX + 256 + d;
    X2[xr] = l0;
    X2[xr + 384] = l1;
    X2[xr + 768] = l2;
    lds01[d][nl] = (unsigned)bc16(l0) | ((unsigned)bc16(l1) << 16);
    lds2[d][nl] = bc16(l2);
  }
  __syncthreads();
#pragma unroll
  for (int i = 0; i < 16; ++i) {
    const int idx = i * 256 + t;
    const int d = idx >> 5, nl = idx & 31;
    const unsigned pk = lds01[d][nl];
    const unsigned short s2 = lds2[d][nl];
    bf16* row = hN2 + (size_t)(b * 128 + d) * LDH + n0 + nl;
    row[0] = bcbf((unsigned short)(pk & 0xffffu));
    row[1024] = bcbf((unsigned short)(pk >> 16));
    row[2048] = bcbf(s2);
  }
}

// ================= elementwise: r gate -> rh3 (3-limb bf16)
__global__ __launch_bounds__(256) void ew1(const float* __restrict__ pre,
                                           const float* __restrict__ u3f,
                                           const float* __restrict__ h,
                                           const float* __restrict__ w4b,
                                           bf16* __restrict__ rh3) {
  const int e4 = blockIdx.x * 256 + threadIdx.x;
  const int r = e4 >> 5;
  const int dq = (e4 & 31) * 4;
  const int b = r & 31, n = r >> 5;
  const f32x4 p = *(const f32x4*)(pre + (size_t)r * 384 + 128 + dq);
  const f32x4 uf = *(const f32x4*)(u3f + (size_t)r * 128 + dq);
  const f32x4 hh = *(const f32x4*)(h + ((size_t)b * 1024 + n) * 128 + dq);
  const f32x4 b4 = *(const f32x4*)(w4b + dq);
  bf16x4 o0, o1, o2;
#pragma unroll
  for (int j = 0; j < 4; ++j) {
    const float rr = sigmoidf_((p[j] + b4[j]) + uf[j]);
    const float v = rr * hh[j];
    o0[j] = (bf16)v;
    float res = v - (float)o0[j];
    o1[j] = (bf16)res;
    res -= (float)o1[j];
    o2[j] = (bf16)res;
  }
  *(bf16x4*)(rh3 + (size_t)r * 384 + dq) = o0;
  *(bf16x4*)(rh3 + (size_t)r * 384 + 128 + dq) = o1;
  *(bf16x4*)(rh3 + (size_t)r * 384 + 256 + dq) = o2;
}

// ================= init kernels
__global__ __launch_bounds__(256) void split_adj(const float* __restrict__ src,
                                                 bf16* __restrict__ dst) {
  const int i = blockIdx.x * 256 + threadIdx.x;  // 1M
  const int r = i >> 10, c = i & 1023;
  const float v = src[i];
  const bf16 l0 = (bf16)v;
  float rr = v - (float)l0;
  const bf16 l1 = (bf16)rr;
  rr -= (float)l1;
  dst[(size_t)r * LDH + c] = l0;
  dst[(size_t)r * LDH + 1024 + c] = l1;
  dst[(size_t)r * LDH + 2048 + c] = (bf16)rr;
}

__global__ void build_wsm(const float* __restrict__ w3, const float* __restrict__ w4,
                          const float* __restrict__ w5, bf16* __restrict__ Wsm) {
  const int k = blockIdx.x * 128 + threadIdx.x;  // 0..255
  const int j = blockIdx.y;                      // 0..383
  float v;
  if (j < 128) v = w3[j * 256 + k];
  else if (j < 256) v = w4[(j - 128) * 256 + k];
  else v = w5[(j - 256) * 256 + k];
  const bf16 l0 = (bf16)v;
  float rr = v - (float)l0;
  const bf16 l1 = (bf16)rr;
  rr -= (float)l1;
  bf16* row = Wsm + (size_t)j * 768 + k;
  row[0] = l0;
  row[256] = l1;
  row[512] = (bf16)rr;
}

__global__ void build_uw(const float* __restrict__ u, bf16* __restrict__ dst) {
  const int i = blockIdx.x * 256 + threadIdx.x;  // 16384
  const int j = i >> 7, k = i & 127;
  const float v = u[i];
  const bf16 l0 = (bf16)v;
  float rr = v - (float)l0;
  const bf16 l1 = (bf16)rr;
  rr -= (float)l1;
  bf16* row = dst + (size_t)j * 384 + k;
  row[0] = l0;
  row[128] = l1;
  row[256] = (bf16)rr;
}

__global__ void sentinel(float* out, int n) {
  const int i = blockIdx.x * 256 + threadIdx.x;
  if (i < n) out[i] = 123456789.f;
}

extern "C" void kernel_launch(void* const* d_in, const int* in_sizes, int n_in,
                              void* d_out, int out_size, void* d_ws, size_t ws_size,
                              hipStream_t stream) {
  const float* input = (const float*)d_in[0];
  const float* Ain = (const float*)d_in[1];
  const float* Aout = (const float*)d_in[2];
  const float* w3w = (const float*)d_in[3];
  const float* w3b = (const float*)d_in[4];
  const float* u3w = (const float*)d_in[5];
  const float* u3b = (const float*)d_in[6];
  const float* w4w = (const float*)d_in[7];
  const float* w4b = (const float*)d_in[8];
  const float* w5w = (const float*)d_in[9];
  const float* w5b = (const float*)d_in[10];
  const float* u5wf = (const float*)d_in[11];
  const float* u5b = (const float*)d_in[12];
  // d_in[13] = time_step; fixed at 5 by the problem spec.

  char* ws = (char*)d_ws;
  size_t off = 0;
  auto alloc = [&](size_t bytes) -> void* {
    void* p = ws + off;
    off += (bytes + 255) & ~(size_t)255;
    return p;
  };
  bf16* A2 = (bf16*)alloc(2048ull * LDH * 2);   // 12.58 MB
  bf16* hN2 = (bf16*)alloc(4096ull * LDH * 2);  // 25.17 MB (rh3 overlay)
  bf16* X2 = (bf16*)alloc(32768ull * LDX * 2);  // 75.50 MB
  bf16* Wsm = (bf16*)alloc(384ull * 768 * 2);
  bf16* u3wb = (bf16*)alloc(128ull * 384 * 2);
  bf16* u5wb = (bf16*)alloc(128ull * 384 * 2);
  float* pre = (float*)alloc(32768ull * 384 * 4);  // 50.33 MB
  float* u3f = (float*)alloc(32768ull * 128 * 4);  // 16.78 MB
  bf16* rh3 = hN2;  // overlay: ew1 writes after adj4 read hN2; pack_h rewrites
  if (off > ws_size) {
    sentinel<<<dim3((out_size + 255) / 256), dim3(256), 0, stream>>>((float*)d_out, out_size);
    return;
  }

  split_adj<<<dim3(4096), dim3(256), 0, stream>>>(Ain, A2);
  split_adj<<<dim3(4096), dim3(256), 0, stream>>>(Aout, A2 + 1024ull * LDH);
  build_wsm<<<dim3(2, 384), dim3(128), 0, stream>>>(w3w, w4w, w5w, Wsm);
  build_uw<<<dim3(64), dim3(256), 0, stream>>>(u3w, u3wb);
  build_uw<<<dim3(64), dim3(256), 0, stream>>>(u5wf, u5wb);

  float* out = (float*)d_out;
  const float* h = input;
  for (int step = 0; step < 5; ++step) {
    pack_h<<<dim3(32, 32), dim3(256), 0, stream>>>(h, hN2, X2);
    // adjacency: M=2048(in|out), N=4096, two-pass kk-outer, direct X2 split
    adj4<<<dim3(32, 16), dim3(256), 0, stream>>>(A2, hN2, X2);
    dense4<<<dim3(4, 256), dim3(256), 0, stream>>>(X2, Wsm, u3wb, u3b, pre, u3f);
    ew1<<<dim3(4096), dim3(256), 0, stream>>>(pre, u3f, h, w4b, rh3);
    u5g<<<dim3(256), dim3(256), 0, stream>>>(rh3, u5wb, pre, u3f, h, w3b, w5b, u5b, out);
    h = out;
  }
}

// Round 9
// 689.435 us; speedup vs baseline: 2.0980x; 1.5766x over previous
//
#include <hip/hip_runtime.h>
#include <cstdint>
#include <cstddef>

// GGNN on MI355X. Round 9: 2-limb f16 / 3-product GEMMs (halves MFMA and LDS
// reads vs the 3-limb bf16 / 6-product scheme; residual 2^-22, dropped l1*l1
// term ~1e-6 abs). Limb-1 stored PRE-SCALED by 2^11 (avoids f16 subnormals);
// products {01,10} accumulate into accC, {00} into accM (k ascending);
// combine v = accM + accC*2^-11 (one rounding). Double-buffered staging with
// counted vmcnt(8). Wave tile 64x64, block 128x128, 2 blocks/CU, slot-XOR
// swizzle (r7-verified, 0 bank conflicts).
// Layouts (f16, limb stride in cols):
//   A2f [2048: Ain|Aout][ l0(1024) | l1'(1024) ]
//   hN2f[b*128+d][ l0(1024) | l1'(1024) ]   (rh2 overlay)
//   X2  [n*32+b][ l0: m_in(128) m_out(128) h(128) | l1': same ]  (LDX 768)
//   Wsm [384: w3|w4|w5][ l0(256) | l1'(256) ]; u3wb/u5wb [128][ l0|l1' (128) ]

typedef _Float16 f16;
typedef __attribute__((ext_vector_type(8))) _Float16 f16x8;
typedef __attribute__((ext_vector_type(4))) float f32x4;

#define LDX 768
#define LDH 2048
#define CSCL 4.8828125e-4f  // 2^-11

static __device__ __forceinline__ void gload16(const void* g, void* l) {
  __builtin_amdgcn_global_load_lds(
      (const __attribute__((address_space(1))) void*)g,
      (__attribute__((address_space(3))) void*)l, 16, 0, 0);
}

static __device__ __forceinline__ float sigmoidf_(float x) {
  return 1.f / (1.f + expf(-x));
}

static __device__ __forceinline__ unsigned short bc16(f16 x) {
  return __builtin_bit_cast(unsigned short, x);
}

// split v into l0 + l1*2^-11 (l1 stored scaled; exact scale, RNE rounding)
static __device__ __forceinline__ void split2(float v, f16& l0, f16& l1) {
  l0 = (f16)v;
  l1 = (f16)((v - (float)l0) * 2048.0f);
}

// ======== 2-limb f16 3-product GEMM core, 128x128 tile, 4 waves (2Mx2N) ======
// A: 128 rows, stride lda, limb l at col (abase + l*aLS + k); B: 128 rows,
// stride ldb, limb l at col (l*bLS + k). nkt = K/32. lds: 2 bufs x 16384 f16
// (A0,A1,B0,B1 planes of [128][32]). accM: main product (k ascending);
// accC: cross products (scaled 2^11).
static __device__ __forceinline__ void gemf(const f16* __restrict__ A, int lda,
                                            int aLS, int abase,
                                            const f16* __restrict__ B, int ldb,
                                            int bLS, int nkt, f16* lds,
                                            f32x4 (&aM)[4][4], f32x4 (&aC)[4][4]) {
  const int t = threadIdx.x;
  const int wave = t >> 6, lane = t & 63;
  const int wr = wave >> 1, wn = wave & 1;
  const int frow = lane & 15;
  const int fk = lane >> 4;                    // 0..3 (16B k-slot)
  const int sl = fk ^ ((frow >> 1) & 3);       // swizzled read slot
  const int gs = (t & 3) ^ ((t >> 3) & 3);     // inverse-swizzled global slot

  // 8 gloads/thread per K-tile: 2 limbs x 2 row-groups x (A,B)
#define STG(buf, kt)                                                          \
  _Pragma("unroll") for (int lb = 0; lb < 2; ++lb)                            \
  _Pragma("unroll") for (int g = 0; g < 2; ++g) {                             \
    const int row_ = g * 64 + (t >> 2);                                       \
    gload16(A + (size_t)row_ * lda + abase + lb * aLS + (kt) * 32 + gs * 8,   \
            lds + (buf) * 16384 + lb * 4096 + g * 2048 + wave * 512);         \
    gload16(B + (size_t)row_ * ldb + lb * bLS + (kt) * 32 + gs * 8,           \
            lds + (buf) * 16384 + 8192 + lb * 4096 + g * 2048 + wave * 512);  \
  }

  STG(0, 0);
  for (int kt = 0; kt < nkt; ++kt) {
    const int cur = kt & 1;
    if (kt + 1 < nkt) {
      STG(cur ^ 1, kt + 1);
      asm volatile("s_waitcnt vmcnt(8)" ::: "memory");  // current buf landed
    } else {
      asm volatile("s_waitcnt vmcnt(0)" ::: "memory");
    }
    __builtin_amdgcn_s_barrier();
    asm volatile("" ::: "memory");

    const f16* bp = lds + cur * 16384;
    f16x8 a0[4], a1[4], b0[4], b1[4];
#pragma unroll
    for (int nf = 0; nf < 4; ++nf) {
      const int row = wn * 64 + nf * 16 + frow;
      b0[nf] = *(const f16x8*)&bp[8192 + row * 32 + sl * 8];
      b1[nf] = *(const f16x8*)&bp[12288 + row * 32 + sl * 8];
    }
#pragma unroll
    for (int mf = 0; mf < 4; ++mf) {
      const int row = wr * 64 + mf * 16 + frow;
      a0[mf] = *(const f16x8*)&bp[row * 32 + sl * 8];
      a1[mf] = *(const f16x8*)&bp[4096 + row * 32 + sl * 8];
    }
    __builtin_amdgcn_s_setprio(1);
    // cross products (scale 2^11) -> accC
#pragma unroll
    for (int mf = 0; mf < 4; ++mf)
#pragma unroll
      for (int nf = 0; nf < 4; ++nf) {
        aC[mf][nf] = __builtin_amdgcn_mfma_f32_16x16x32_f16(a0[mf], b1[nf],
                                                            aC[mf][nf], 0, 0, 0);
        aC[mf][nf] = __builtin_amdgcn_mfma_f32_16x16x32_f16(a1[mf], b0[nf],
                                                            aC[mf][nf], 0, 0, 0);
      }
    // main product, k ascending -> accM
#pragma unroll
    for (int mf = 0; mf < 4; ++mf)
#pragma unroll
      for (int nf = 0; nf < 4; ++nf)
        aM[mf][nf] = __builtin_amdgcn_mfma_f32_16x16x32_f16(a0[mf], b0[nf],
                                                            aM[mf][nf], 0, 0, 0);
    __builtin_amdgcn_s_setprio(0);
    asm volatile("" ::: "memory");
    __builtin_amdgcn_s_barrier();  // all reads done -> buf reusable
  }
#undef STG
}

#define ACC_ZERO(acc)                          \
  _Pragma("unroll") for (int i = 0; i < 4; ++i) \
  _Pragma("unroll") for (int j = 0; j < 4; ++j) acc[i][j] = {0.f, 0.f, 0.f, 0.f};

// ================= adjacency: M=2048(in|out), N=4096, K=1024
__global__ __launch_bounds__(256, 2) void adjf(const f16* __restrict__ A2f,
                                               const f16* __restrict__ hN2f,
                                               f16* __restrict__ X2) {
  __shared__ f16 lds[32768];
  const int m0 = blockIdx.y * 128;
  const int n0 = blockIdx.x * 128;
  f32x4 aM[4][4], aC[4][4];
  ACC_ZERO(aM);
  ACC_ZERO(aC);
  gemf(A2f + (size_t)m0 * LDH, LDH, 1024, 0, hN2f + (size_t)n0 * LDH, LDH, 1024,
       32, lds, aM, aC);

  const int lane = threadIdx.x & 63, wave = threadIdx.x >> 6;
  const int rb = m0 + (wave >> 1) * 64 + (lane >> 4) * 4;
  const int cb = n0 + (wave & 1) * 64 + (lane & 15);
#pragma unroll
  for (int mf = 0; mf < 4; ++mf)
#pragma unroll
    for (int nf = 0; nf < 4; ++nf)
#pragma unroll
      for (int j = 0; j < 4; ++j) {
        const int gr = rb + mf * 16 + j;
        const int gc = cb + nf * 16;
        const float v = aM[mf][nf][j] + aC[mf][nf][j] * CSCL;
        const int node = gr & 1023;
        const int coff = (gr >> 10) * 128;  // 0: m_in, 128: m_out
        const int bb = gc >> 7, d = gc & 127;
        f16* px = X2 + ((size_t)node * 32 + bb) * LDX + coff + d;
        f16 l0, l1;
        split2(v, l0, l1);
        px[0] = l0;
        px[384] = l1;
      }
}

// ================= dense: bx<3 -> pre[.][bx*128..]; bx==3 -> u3f (+u3b)
__global__ __launch_bounds__(256, 2) void densef(const f16* __restrict__ X2,
                                                 const f16* __restrict__ Wsm,
                                                 const f16* __restrict__ u3wb,
                                                 const float* __restrict__ u3b,
                                                 float* __restrict__ pre,
                                                 float* __restrict__ u3f) {
  __shared__ f16 lds[32768];
  const int m0 = blockIdx.y * 128;
  const int bx = blockIdx.x;
  f32x4 aM[4][4], aC[4][4];
  ACC_ZERO(aM);
  ACC_ZERO(aC);
  const int lane = threadIdx.x & 63, wave = threadIdx.x >> 6;
  const int rb = m0 + (wave >> 1) * 64 + (lane >> 4) * 4;
  const int cb = (wave & 1) * 64 + (lane & 15);
  if (bx < 3) {
    gemf(X2 + (size_t)m0 * LDX, LDX, 384, 0, Wsm + (size_t)bx * 128 * 512, 512, 256,
         8, lds, aM, aC);
#pragma unroll
    for (int mf = 0; mf < 4; ++mf)
#pragma unroll
      for (int nf = 0; nf < 4; ++nf)
#pragma unroll
        for (int j = 0; j < 4; ++j)
          pre[(size_t)(rb + mf * 16 + j) * 384 + bx * 128 + cb + nf * 16] =
              aM[mf][nf][j] + aC[mf][nf][j] * CSCL;
  } else {
    gemf(X2 + (size_t)m0 * LDX, LDX, 384, 256, u3wb, 256, 128, 4, lds, aM, aC);
#pragma unroll
    for (int mf = 0; mf < 4; ++mf)
#pragma unroll
      for (int nf = 0; nf < 4; ++nf)
#pragma unroll
        for (int j = 0; j < 4; ++j) {
          const int gc = cb + nf * 16;
          const float v = aM[mf][nf][j] + aC[mf][nf][j] * CSCL;
          // np: u3 = (h@u3w^T) + u3b, rounded once
          u3f[(size_t)(rb + mf * 16 + j) * 128 + gc] = v + u3b[gc];
        }
  }
}

// ================= u5 GEMM + fused ew2 epilogue (z, hv, h' -> out)
__global__ __launch_bounds__(256, 2) void u5g(const f16* __restrict__ rh2,
                                              const f16* __restrict__ u5wb,
                                              const float* __restrict__ pre,
                                              const float* __restrict__ u3f,
                                              const float* __restrict__ h,
                                              const float* __restrict__ w3b,
                                              const float* __restrict__ w5b,
                                              const float* __restrict__ u5b,
                                              float* __restrict__ out) {
  __shared__ f16 lds[32768];
  const int m0 = blockIdx.x * 128;
  f32x4 aM[4][4], aC[4][4];
  ACC_ZERO(aM);
  ACC_ZERO(aC);
  gemf(rh2 + (size_t)m0 * 256, 256, 128, 0, u5wb, 256, 128, 4, lds, aM, aC);

  const int lane = threadIdx.x & 63, wave = threadIdx.x >> 6;
  const int rb = m0 + (wave >> 1) * 64 + (lane >> 4) * 4;
  const int cb = (wave & 1) * 64 + (lane & 15);
#pragma unroll
  for (int mf = 0; mf < 4; ++mf)
#pragma unroll
    for (int nf = 0; nf < 4; ++nf)
#pragma unroll
      for (int j = 0; j < 4; ++j) {
        const int gr = rb + mf * 16 + j;
        const int gc = cb + nf * 16;
        const float v = aM[mf][nf][j] + aC[mf][nf][j] * CSCL;
        const float u5f = v + u5b[gc];  // np: U5 + u5b
        const float z = sigmoidf_((pre[(size_t)gr * 384 + gc] + w3b[gc]) +
                                  u3f[(size_t)gr * 128 + gc]);
        const float hv = tanhf((pre[(size_t)gr * 384 + 256 + gc] + w5b[gc]) + u5f);
        const int bb = gr & 31, node = gr >> 5;
        const size_t hi = ((size_t)bb * 1024 + node) * 128 + gc;
        const float hh = h[hi];
        out[hi] = (1.f - z) * hh + z * hv;  // np: (1-z)*h + z*hv
      }
}

// ================= pack h (fp32 [B][N][D]) -> hN2f 2-limb + X2 h-cols 2-limb
__global__ __launch_bounds__(256) void pack_h(const float* __restrict__ h,
                                              f16* __restrict__ hN2f,
                                              f16* __restrict__ X2) {
  __shared__ unsigned int lds01[128][33];
  const int t = threadIdx.x;
  const int b = blockIdx.y;
  const int n0 = blockIdx.x * 32;
#pragma unroll
  for (int i = 0; i < 16; ++i) {
    const int idx = i * 256 + t;
    const int nl = idx >> 7, d = idx & 127;
    const float v = h[((size_t)b * 1024 + n0 + nl) * 128 + d];
    f16 l0, l1;
    split2(v, l0, l1);
    const size_t xr = ((size_t)(n0 + nl) * 32 + b) * LDX + 256 + d;
    X2[xr] = l0;
    X2[xr + 384] = l1;
    lds01[d][nl] = (unsigned)bc16(l0) | ((unsigned)bc16(l1) << 16);
  }
  __syncthreads();
#pragma unroll
  for (int i = 0; i < 16; ++i) {
    const int idx = i * 256 + t;
    const int d = idx >> 5, nl = idx & 31;
    const unsigned pk = lds01[d][nl];
    f16* row = hN2f + (size_t)(b * 128 + d) * LDH + n0 + nl;
    row[0] = __builtin_bit_cast(f16, (unsigned short)(pk & 0xffffu));
    row[1024] = __builtin_bit_cast(f16, (unsigned short)(pk >> 16));
  }
}

// ================= elementwise: r gate -> rh2 (2-limb f16)
__global__ __launch_bounds__(256) void ew1(const float* __restrict__ pre,
                                           const float* __restrict__ u3f,
                                           const float* __restrict__ h,
                                           const float* __restrict__ w4b,
                                           f16* __restrict__ rh2) {
  const int e4 = blockIdx.x * 256 + threadIdx.x;
  const int r = e4 >> 5;
  const int dq = (e4 & 31) * 4;
  const int b = r & 31, n = r >> 5;
  const f32x4 p = *(const f32x4*)(pre + (size_t)r * 384 + 128 + dq);
  const f32x4 uf = *(const f32x4*)(u3f + (size_t)r * 128 + dq);
  const f32x4 hh = *(const f32x4*)(h + ((size_t)b * 1024 + n) * 128 + dq);
  const f32x4 b4 = *(const f32x4*)(w4b + dq);
  f16 o0[4], o1[4];
#pragma unroll
  for (int j = 0; j < 4; ++j) {
    const float rr = sigmoidf_((p[j] + b4[j]) + uf[j]);
    const float v = rr * hh[j];
    split2(v, o0[j], o1[j]);
  }
  *(ulong1*)&rh2[(size_t)r * 256 + dq] = *(ulong1*)o0;
  *(ulong1*)&rh2[(size_t)r * 256 + 128 + dq] = *(ulong1*)o1;
}

// ================= init kernels
__global__ __launch_bounds__(256) void split_adjf(const float* __restrict__ src,
                                                  f16* __restrict__ dst) {
  const int i = blockIdx.x * 256 + threadIdx.x;  // 1M
  const int r = i >> 10, c = i & 1023;
  f16 l0, l1;
  split2(src[i], l0, l1);
  dst[(size_t)r * LDH + c] = l0;
  dst[(size_t)r * LDH + 1024 + c] = l1;
}

__global__ void build_wsm(const float* __restrict__ w3, const float* __restrict__ w4,
                          const float* __restrict__ w5, f16* __restrict__ Wsm) {
  const int k = blockIdx.x * 128 + threadIdx.x;  // 0..255
  const int j = blockIdx.y;                      // 0..383
  float v;
  if (j < 128) v = w3[j * 256 + k];
  else if (j < 256) v = w4[(j - 128) * 256 + k];
  else v = w5[(j - 256) * 256 + k];
  f16 l0, l1;
  split2(v, l0, l1);
  Wsm[(size_t)j * 512 + k] = l0;
  Wsm[(size_t)j * 512 + 256 + k] = l1;
}

__global__ void build_uw(const float* __restrict__ u, f16* __restrict__ dst) {
  const int i = blockIdx.x * 256 + threadIdx.x;  // 16384
  const int j = i >> 7, k = i & 127;
  f16 l0, l1;
  split2(u[i], l0, l1);
  dst[(size_t)j * 256 + k] = l0;
  dst[(size_t)j * 256 + 128 + k] = l1;
}

__global__ void sentinel(float* out, int n) {
  const int i = blockIdx.x * 256 + threadIdx.x;
  if (i < n) out[i] = 123456789.f;
}

extern "C" void kernel_launch(void* const* d_in, const int* in_sizes, int n_in,
                              void* d_out, int out_size, void* d_ws, size_t ws_size,
                              hipStream_t stream) {
  const float* input = (const float*)d_in[0];
  const float* Ain = (const float*)d_in[1];
  const float* Aout = (const float*)d_in[2];
  const float* w3w = (const float*)d_in[3];
  const float* w3b = (const float*)d_in[4];
  const float* u3w = (const float*)d_in[5];
  const float* u3b = (const float*)d_in[6];
  const float* w4w = (const float*)d_in[7];
  const float* w4b = (const float*)d_in[8];
  const float* w5w = (const float*)d_in[9];
  const float* w5b = (const float*)d_in[10];
  const float* u5wf = (const float*)d_in[11];
  const float* u5b = (const float*)d_in[12];
  // d_in[13] = time_step; fixed at 5 by the problem spec.

  char* ws = (char*)d_ws;
  size_t off = 0;
  auto alloc = [&](size_t bytes) -> void* {
    void* p = ws + off;
    off += (bytes + 255) & ~(size_t)255;
    return p;
  };
  f16* A2f = (f16*)alloc(2048ull * LDH * 2);    // 8.39 MB
  f16* hN2f = (f16*)alloc(4096ull * LDH * 2);   // 16.78 MB (rh2 overlay)
  f16* X2 = (f16*)alloc(32768ull * LDX * 2);    // 50.33 MB
  f16* Wsm = (f16*)alloc(384ull * 512 * 2);
  f16* u3wb = (f16*)alloc(128ull * 256 * 2);
  f16* u5wb = (f16*)alloc(128ull * 256 * 2);
  float* pre = (float*)alloc(32768ull * 384 * 4);  // 50.33 MB
  float* u3f = (float*)alloc(32768ull * 128 * 4);  // 16.78 MB
  f16* rh2 = hN2f;  // overlay: ew1 writes after adjf read hN2f; pack_h rewrites
  if (off > ws_size) {
    sentinel<<<dim3((out_size + 255) / 256), dim3(256), 0, stream>>>((float*)d_out, out_size);
    return;
  }

  split_adjf<<<dim3(4096), dim3(256), 0, stream>>>(Ain, A2f);
  split_adjf<<<dim3(4096), dim3(256), 0, stream>>>(Aout, A2f + 1024ull * LDH);
  build_wsm<<<dim3(2, 384), dim3(128), 0, stream>>>(w3w, w4w, w5w, Wsm);
  build_uw<<<dim3(64), dim3(256), 0, stream>>>(u3w, u3wb);
  build_uw<<<dim3(64), dim3(256), 0, stream>>>(u5wf, u5wb);

  float* out = (float*)d_out;
  const float* h = input;
  for (int step = 0; step < 5; ++step) {
    pack_h<<<dim3(32, 32), dim3(256), 0, stream>>>(h, hN2f, X2);
    adjf<<<dim3(32, 16), dim3(256), 0, stream>>>(A2f, hN2f, X2);
    densef<<<dim3(4, 256), dim3(256), 0, stream>>>(X2, Wsm, u3wb, u3b, pre, u3f);
    ew1<<<dim3(4096), dim3(256), 0, stream>>>(pre, u3f, h, w4b, rh2);
    u5g<<<dim3(256), dim3(256), 0, stream>>>(rh2, u5wb, pre, u3f, h, w3b, w5b, u5b, out);
    h = out;
  }
}